// Round 15
// baseline (29.343 us; speedup 1.0000x reference)
//
#include <hip/hip_runtime.h>

typedef float f32x4 __attribute__((ext_vector_type(4)));

// Problem constants: x [B,C,T] fp32 -> out [B,C,T] fp32.
#define B_ 32
#define C_ 256
#define T_ 2048

// R5:  plain stores (L2 write-combining), never nontemporal.
// R7:  strided global loads cap ~2.6 TB/s -> coalesced only.
// R8:  XOR-swizzled b128 LDS reads conflict-free.
// R10: coalesced stores via LDS round-trip: 40->31 us.
// R14: no global_load_lds; reg-staging + continuous issue: 30.5->28.3 us.
// R15: pipelining consumes TLP (NR=4 -> only 2 waves/SIMD). Flip the trade:
//   NR=1, 8192 waves, 16 waves/CU. Single vmcnt(0)/wave hidden by TLP.

#define STEP(X0, XP1, O) { \
    float y = w0 * xm1;  y = y + w1 * (X0);  y = y + w2 * (XP1); \
    y = y + bb;  y = y * inv;  y = y + add; \
    float dv = (y - v) * 0.5f;  v = v + dv; \
    float s = (v >= 1.0f) ? 1.0f : 0.0f; \
    (O) = s + (X0); \
    v = (v >= 1.0f) ? 0.0f : v; \
    xm1 = (X0); }

#define Q4(BV, NX, O) \
    STEP(BV.x, BV.y, O.x) STEP(BV.y, BV.z, O.y) \
    STEP(BV.z, BV.w, O.z) STEP(BV.w, NX,   O.w)

#define LDPH(p0,p1,p2,p3,p4,p5,p6,p7, GC) { \
    const int _m = ((GC) >> 3) & 7; \
    const float* _bp = wl + ((GC) << 2); \
    p0 = *(const f32x4*)(_bp + ((0 ^ _m) << 2)); \
    p1 = *(const f32x4*)(_bp + ((1 ^ _m) << 2)); \
    p2 = *(const f32x4*)(_bp + ((2 ^ _m) << 2)); \
    p3 = *(const f32x4*)(_bp + ((3 ^ _m) << 2)); \
    p4 = *(const f32x4*)(_bp + ((4 ^ _m) << 2)); \
    p5 = *(const f32x4*)(_bp + ((5 ^ _m) << 2)); \
    p6 = *(const f32x4*)(_bp + ((6 ^ _m) << 2)); \
    p7 = *(const f32x4*)(_bp + ((7 ^ _m) << 2)); }

#define PHC(r0,r1,r2,r3,r4,r5,r6,r7, PEEK) { \
    f32x4 _d; \
    Q4(r0, r1.x, _d) Q4(r1, r2.x, _d) Q4(r2, r3.x, _d) Q4(r3, r4.x, _d) \
    Q4(r4, r5.x, _d) Q4(r5, r6.x, _d) Q4(r6, r7.x, _d) Q4(r7, (PEEK), _d) }

__device__ __forceinline__ int swzg(int g) { return g ^ ((g >> 3) & 7); }

__global__ __launch_bounds__(128, 4) void cpe_lif_kernel(
    const float* __restrict__ x, const float* __restrict__ w,
    const float* __restrict__ cb, const float* __restrict__ gamma,
    const float* __restrict__ beta, const float* __restrict__ rmean,
    const float* __restrict__ rvar, float* __restrict__ out)
{
#pragma clang fp contract(off)   // match np reference rounding op-for-op
    __shared__ __align__(16) float lds[2 * T_];   // 16 KiB: one 8 KiB buf/wave

    const int tid = threadIdx.x;
    const int wid = __builtin_amdgcn_readfirstlane(tid >> 6);  // uniform
    const int l   = tid & 63;

    const int row = blockIdx.x * 2 + wid;          // one row per wave
    const int ch  = row & (C_ - 1);

    // Per-channel constants, numpy-port op order (all fp32, correctly rounded).
    const float w0 = w[ch * 3 + 0], w1 = w[ch * 3 + 1], w2 = w[ch * 3 + 2];
    const float bb = cb[ch];
    const float sq  = sqrtf(rvar[ch] + 1e-5f);
    const float rs  = 1.0f / sq;
    const float inv = gamma[ch] * rs;
    const float add = beta[ch] - rmean[ch] * inv;

    const float* xr   = x   + (size_t)row * T_;
    float*       outr = out + (size_t)row * T_;
    float*       wl   = lds + wid * T_;

    const int lsrc = l ^ ((l >> 3) & 7);

    // ---- Stage row via registers (coalesced 1 KB per instruction), then
    // ds_write so LDS granule s holds global granule swzg(s) (R13-proven).
    f32x4 p0,p1,p2,p3,p4,p5,p6,p7;
    p0 = *(const f32x4*)(xr + ((0 * 64 + lsrc) << 2));
    p1 = *(const f32x4*)(xr + ((1 * 64 + lsrc) << 2));
    p2 = *(const f32x4*)(xr + ((2 * 64 + lsrc) << 2));
    p3 = *(const f32x4*)(xr + ((3 * 64 + lsrc) << 2));
    p4 = *(const f32x4*)(xr + ((4 * 64 + lsrc) << 2));
    p5 = *(const f32x4*)(xr + ((5 * 64 + lsrc) << 2));
    p6 = *(const f32x4*)(xr + ((6 * 64 + lsrc) << 2));
    p7 = *(const f32x4*)(xr + ((7 * 64 + lsrc) << 2));
    __builtin_amdgcn_sched_barrier(0);
    asm volatile("s_waitcnt vmcnt(0)" ::: "memory");   // hidden by co-resident waves
    __builtin_amdgcn_sched_barrier(0);
    *(f32x4*)(wl + ((0 * 64 + l) << 2)) = p0;
    *(f32x4*)(wl + ((1 * 64 + l) << 2)) = p1;
    *(f32x4*)(wl + ((2 * 64 + l) << 2)) = p2;
    *(f32x4*)(wl + ((3 * 64 + l) << 2)) = p3;
    *(f32x4*)(wl + ((4 * 64 + l) << 2)) = p4;
    *(f32x4*)(wl + ((5 * 64 + l) << 2)) = p5;
    *(f32x4*)(wl + ((6 * 64 + l) << 2)) = p6;
    *(f32x4*)(wl + ((7 * 64 + l) << 2)) = p7;

    // ---- Scan (R10/R12 body, bitwise-proven): 64-elem lookback + own 32.
    const int G2  = 8 * l;
    const int G1c = (l >= 1) ? G2 - 8  : 0;
    const int G0c = (l >= 2) ? G2 - 16 : 0;
    const int gt  = (l >= 3) ? (G2 - 17) : 0;
    const f32x4 tail = *(const f32x4*)(wl + (swzg(gt) << 2));
    float xm1 = (l >= 3) ? tail.w : 0.0f;
    float v = 0.0f;

    f32x4 a0,a1,a2,a3,a4,a5,a6,a7;
    f32x4 b0,b1,b2,b3,b4,b5,b6,b7;
    f32x4 c0,c1,c2,c3,c4,c5,c6,c7;

    LDPH(a0,a1,a2,a3,a4,a5,a6,a7, G0c)
    LDPH(b0,b1,b2,b3,b4,b5,b6,b7, G1c)
    c0 = *(const f32x4*)(wl + ((G2 + (0 ^ (l & 7))) << 2));

    if (l >= 2) { PHC(a0,a1,a2,a3,a4,a5,a6,a7, b0.x) }

    {
        const int _m = l & 7;
        const float* _bp = wl + (G2 << 2);
        c1 = *(const f32x4*)(_bp + ((1 ^ _m) << 2));
        c2 = *(const f32x4*)(_bp + ((2 ^ _m) << 2));
        c3 = *(const f32x4*)(_bp + ((3 ^ _m) << 2));
        c4 = *(const f32x4*)(_bp + ((4 ^ _m) << 2));
        c5 = *(const f32x4*)(_bp + ((5 ^ _m) << 2));
        c6 = *(const f32x4*)(_bp + ((6 ^ _m) << 2));
        c7 = *(const f32x4*)(_bp + ((7 ^ _m) << 2));
    }
    const int gp = (l < 63) ? (G2 + 8) : 0;
    const f32x4 pk = *(const f32x4*)(wl + (swzg(gp) << 2));
    const float peekOwn = (l == 63) ? 0.0f : pk.x;

    if (l >= 1) { PHC(b0,b1,b2,b3,b4,b5,b6,b7, c0.x) }

    f32x4 o0,o1,o2,o3,o4,o5,o6,o7;
    Q4(c0, c1.x, o0) Q4(c1, c2.x, o1) Q4(c2, c3.x, o2) Q4(c3, c4.x, o3)
    Q4(c4, c5.x, o4) Q4(c5, c6.x, o5) Q4(c6, c7.x, o6) Q4(c7, peekOwn, o7)

    {   // LDS writeback (swzg bijection; wave-private slice; DS pipe in-order)
        const int m8 = l & 7;
        float* wb = wl + (G2 << 2);
        *(f32x4*)(wb + ((0 ^ m8) << 2)) = o0;
        *(f32x4*)(wb + ((1 ^ m8) << 2)) = o1;
        *(f32x4*)(wb + ((2 ^ m8) << 2)) = o2;
        *(f32x4*)(wb + ((3 ^ m8) << 2)) = o3;
        *(f32x4*)(wb + ((4 ^ m8) << 2)) = o4;
        *(f32x4*)(wb + ((5 ^ m8) << 2)) = o5;
        *(f32x4*)(wb + ((6 ^ m8) << 2)) = o6;
        *(f32x4*)(wb + ((7 ^ m8) << 2)) = o7;
    }

    // ---- Coalesced 1 KB stores (readback transpose), fire-and-forget.
    #pragma unroll
    for (int i = 0; i < 8; ++i) {
        const f32x4 rb = *(const f32x4*)(wl + ((i * 64 + lsrc) << 2));
        *(f32x4*)(outr + i * 256 + (l << 2)) = rb;
    }
}

extern "C" void kernel_launch(void* const* d_in, const int* in_sizes, int n_in,
                              void* d_out, int out_size, void* d_ws, size_t ws_size,
                              hipStream_t stream) {
    const float* x     = (const float*)d_in[0];
    const float* w     = (const float*)d_in[1];
    const float* cb    = (const float*)d_in[2];
    const float* gamma = (const float*)d_in[3];
    const float* beta  = (const float*)d_in[4];
    const float* rmean = (const float*)d_in[5];
    const float* rvar  = (const float*)d_in[6];
    float* out = (float*)d_out;

    // 8192 rows, 1 row/wave, 2 waves/block -> 4096 blocks.
    const int grid = (B_ * C_) / 2;
    cpe_lif_kernel<<<grid, 128, 0, stream>>>(x, w, cb, gamma, beta, rmean, rvar, out);
}

// Round 16
// 28.956 us; speedup vs baseline: 1.0134x; 1.0134x over previous
//
#include <hip/hip_runtime.h>

typedef float f32x4 __attribute__((ext_vector_type(4)));

// Problem constants: x [B,C,T] fp32 -> out [B,C,T] fp32.
#define B_ 32
#define C_ 256
#define T_ 2048

// R5:  plain stores (L2 write-combining), never nontemporal.
// R7:  strided global loads cap ~2.6 TB/s -> coalesced only.
// R10: coalesced stores via LDS round-trip.
// R14: reg-staging + continuous issue + pipelining: 28.3 us (best).
// R15: TLP falsified 3rd time. 28.3 ~= VALU(15.3) + HBM(16) sum.
// R16: cut lookback amplification 3x->2x: CHUNK=64/lane, 32 lanes/row,
//   2 rows/wave via lane groups. Transposed-XOR LDS layout (both ds_write
//   and ds_read computed -> free choice): granule g=(j<<4)|k stored at
//   (k<<5)|(j^k). All four access patterns verified uniform (8 granules
//   per 4-bank slot = b128 minimum).

#define STEP(X0, XP1, O) { \
    float y = w0 * xm1;  y = y + w1 * (X0);  y = y + w2 * (XP1); \
    y = y + bb;  y = y * inv;  y = y + add; \
    float dv = (y - v) * 0.5f;  v = v + dv; \
    float s = (v >= 1.0f) ? 1.0f : 0.0f; \
    (O) = s + (X0); \
    v = (v >= 1.0f) ? 0.0f : v; \
    xm1 = (X0); }

#define Q4(BV, NX, O) \
    STEP(BV.x, BV.y, O.x) STEP(BV.y, BV.z, O.y) \
    STEP(BV.z, BV.w, O.z) STEP(BV.w, NX,   O.w)

#define PHC(r0,r1,r2,r3,r4,r5,r6,r7, PEEK) { \
    f32x4 _d; \
    Q4(r0, r1.x, _d) Q4(r1, r2.x, _d) Q4(r2, r3.x, _d) Q4(r3, r4.x, _d) \
    Q4(r4, r5.x, _d) Q4(r5, r6.x, _d) Q4(r6, r7.x, _d) Q4(r7, (PEEK), _d) }

// Transposed-XOR layout: global granule (j<<4)|k at LDS granule (k<<5)|(j^k).
__device__ __forceinline__ int lgp(int j, int k) {
    return (((k) << 5) | ((j) ^ (k))) << 2;   // float offset within slice
}

#define RD8(d0,d1,d2,d3,d4,d5,d6,d7, SL, J, KB) \
    d0 = *(const f32x4*)((SL) + lgp((J), (KB)+0)); \
    d1 = *(const f32x4*)((SL) + lgp((J), (KB)+1)); \
    d2 = *(const f32x4*)((SL) + lgp((J), (KB)+2)); \
    d3 = *(const f32x4*)((SL) + lgp((J), (KB)+3)); \
    d4 = *(const f32x4*)((SL) + lgp((J), (KB)+4)); \
    d5 = *(const f32x4*)((SL) + lgp((J), (KB)+5)); \
    d6 = *(const f32x4*)((SL) + lgp((J), (KB)+6)); \
    d7 = *(const f32x4*)((SL) + lgp((J), (KB)+7));

#define WR8(SL, J, KB, s0,s1,s2,s3,s4,s5,s6,s7) \
    *(f32x4*)((SL) + lgp((J), (KB)+0)) = s0; \
    *(f32x4*)((SL) + lgp((J), (KB)+1)) = s1; \
    *(f32x4*)((SL) + lgp((J), (KB)+2)) = s2; \
    *(f32x4*)((SL) + lgp((J), (KB)+3)) = s3; \
    *(f32x4*)((SL) + lgp((J), (KB)+4)) = s4; \
    *(f32x4*)((SL) + lgp((J), (KB)+5)) = s5; \
    *(f32x4*)((SL) + lgp((J), (KB)+6)) = s6; \
    *(f32x4*)((SL) + lgp((J), (KB)+7)) = s7;

// Coalesced 1 KB global loads: lane l takes granule i*64+l of the row.
#define PLOADROW(XS, P0,P1,P2,P3,P4,P5,P6,P7) \
    P0 = *(const f32x4*)((XS) + 0*256 + (l<<2)); \
    P1 = *(const f32x4*)((XS) + 1*256 + (l<<2)); \
    P2 = *(const f32x4*)((XS) + 2*256 + (l<<2)); \
    P3 = *(const f32x4*)((XS) + 3*256 + (l<<2)); \
    P4 = *(const f32x4*)((XS) + 4*256 + (l<<2)); \
    P5 = *(const f32x4*)((XS) + 5*256 + (l<<2)); \
    P6 = *(const f32x4*)((XS) + 6*256 + (l<<2)); \
    P7 = *(const f32x4*)((XS) + 7*256 + (l<<2));

// Staged regs -> LDS at transposed-XOR positions (granule 64i+l).
#define DSWROW(SLB, P0,P1,P2,P3,P4,P5,P6,P7) \
    *(f32x4*)((SLB) + lgp(4*0 + lh, lk)) = P0; \
    *(f32x4*)((SLB) + lgp(4*1 + lh, lk)) = P1; \
    *(f32x4*)((SLB) + lgp(4*2 + lh, lk)) = P2; \
    *(f32x4*)((SLB) + lgp(4*3 + lh, lk)) = P3; \
    *(f32x4*)((SLB) + lgp(4*4 + lh, lk)) = P4; \
    *(f32x4*)((SLB) + lgp(4*5 + lh, lk)) = P5; \
    *(f32x4*)((SLB) + lgp(4*6 + lh, lk)) = P6; \
    *(f32x4*)((SLB) + lgp(4*7 + lh, lk)) = P7;

// Readback (inverse transpose): lane l fetches granule i*64+l of the row.
#define RBROW(SLB, Q0,Q1,Q2,Q3,Q4_,Q5,Q6,Q7) \
    Q0  = *(const f32x4*)((SLB) + lgp(4*0 + lh, lk)); \
    Q1  = *(const f32x4*)((SLB) + lgp(4*1 + lh, lk)); \
    Q2  = *(const f32x4*)((SLB) + lgp(4*2 + lh, lk)); \
    Q3  = *(const f32x4*)((SLB) + lgp(4*3 + lh, lk)); \
    Q4_ = *(const f32x4*)((SLB) + lgp(4*4 + lh, lk)); \
    Q5  = *(const f32x4*)((SLB) + lgp(4*5 + lh, lk)); \
    Q6  = *(const f32x4*)((SLB) + lgp(4*6 + lh, lk)); \
    Q7  = *(const f32x4*)((SLB) + lgp(4*7 + lh, lk));

#define STROW(OP, Q0,Q1,Q2,Q3,Q4_,Q5,Q6,Q7) \
    *(f32x4*)((OP) + 0*256 + (l<<2)) = Q0; \
    *(f32x4*)((OP) + 1*256 + (l<<2)) = Q1; \
    *(f32x4*)((OP) + 2*256 + (l<<2)) = Q2; \
    *(f32x4*)((OP) + 3*256 + (l<<2)) = Q3; \
    *(f32x4*)((OP) + 4*256 + (l<<2)) = Q4_; \
    *(f32x4*)((OP) + 5*256 + (l<<2)) = Q5; \
    *(f32x4*)((OP) + 6*256 + (l<<2)) = Q6; \
    *(f32x4*)((OP) + 7*256 + (l<<2)) = Q7;

__global__ __launch_bounds__(128, 2) void cpe_lif_kernel(
    const float* __restrict__ x, const float* __restrict__ w,
    const float* __restrict__ cb, const float* __restrict__ gamma,
    const float* __restrict__ beta, const float* __restrict__ rmean,
    const float* __restrict__ rvar, float* __restrict__ out)
{
#pragma clang fp contract(off)   // match np reference rounding op-for-op
    __shared__ __align__(16) float lds[2 * 2 * T_];   // 32 KiB: 2 waves x 2 rows

    const int tid = threadIdx.x;
    const int wid = __builtin_amdgcn_readfirstlane(tid >> 6);  // uniform
    const int l   = tid & 63;
    const int g   = l >> 5;        // lane group = row within iteration
    const int j   = l & 31;        // lane-in-row: owns elems [64j, 64j+64)
    const int lh  = l >> 4;
    const int lk  = l & 15;

    const int wrow = (blockIdx.x * 2 + wid) * 4;   // 4 rows per wave (2 its x 2)
    const float* xbase = x   + (size_t)wrow * T_;
    float*       obase = out + (size_t)wrow * T_;
    float* wl = lds + wid * (2 * T_);
    float* sA = wl;                // row-A slice (2048 floats)
    float* sB = wl + T_;           // row-B slice
    float* sl = wl + g * T_;       // this lane group's scan slice

    // Per-iteration channel constants (per-lane: group-dependent row).
    // All loads BEFORE any staging VMEM so the vmcnt FIFO stays clean.
    const int ch0 = (wrow + g) & (C_ - 1);
    const int ch1 = (wrow + 2 + g) & (C_ - 1);
    const float w0a = w[ch0*3+0], w1a = w[ch0*3+1], w2a = w[ch0*3+2];
    const float bba = cb[ch0], vva = rvar[ch0], gga = gamma[ch0];
    const float bta = beta[ch0], mma = rmean[ch0];
    const float w0b = w[ch1*3+0], w1b = w[ch1*3+1], w2b = w[ch1*3+2];
    const float bbv = cb[ch1], vvb = rvar[ch1], ggb = gamma[ch1];
    const float btb = beta[ch1], mmb = rmean[ch1];

    f32x4 pA0,pA1,pA2,pA3,pA4,pA5,pA6,pA7;
    f32x4 pB0,pB1,pB2,pB3,pB4,pB5,pB6,pB7;
    PLOADROW(xbase,       pA0,pA1,pA2,pA3,pA4,pA5,pA6,pA7)
    PLOADROW(xbase + T_,  pB0,pB1,pB2,pB3,pB4,pB5,pB6,pB7)
    __builtin_amdgcn_sched_barrier(0);
    asm volatile("s_waitcnt vmcnt(0)" ::: "memory");   // drains consts too
    __builtin_amdgcn_sched_barrier(0);

    // Derived constants, numpy-port op order (fp32, correctly rounded).
    const float sqa = sqrtf(vva + 1e-5f), rsa = 1.0f / sqa;
    const float inva = gga * rsa, adda = bta - mma * inva;
    const float sqb = sqrtf(vvb + 1e-5f), rsb = 1.0f / sqb;
    const float invb = ggb * rsb, addb = btb - mmb * invb;

    DSWROW(sA, pA0,pA1,pA2,pA3,pA4,pA5,pA6,pA7)
    DSWROW(sB, pB0,pB1,pB2,pB3,pB4,pB5,pB6,pB7)

#pragma clang loop unroll(disable)
    for (int it = 0; it < 2; ++it) {
        if (it == 0) {   // continuous issue: prefetch next 2 rows into regs
            PLOADROW(xbase + 2*T_, pA0,pA1,pA2,pA3,pA4,pA5,pA6,pA7)
            PLOADROW(xbase + 3*T_, pB0,pB1,pB2,pB3,pB4,pB5,pB6,pB7)
        }
        __builtin_amdgcn_sched_barrier(0);

        const float w0 = it ? w0b : w0a, w1 = it ? w1b : w1a;
        const float w2 = it ? w2b : w2a, bb = it ? bbv : bba;
        const float inv = it ? invb : inva, add = it ? addb : adda;

        // ---- scan: 64-elem lookback (lane j-1's chunk) + own 64 elems.
        const int jl = (j >= 1) ? j - 1 : 0;
        const int jt = (j >= 2) ? j - 2 : 0;
        const f32x4 rt = *(const f32x4*)(sl + lgp(jt, 15));  // elem 64j-65
        float xm1 = (j >= 2) ? rt.w : 0.0f;   // j<=1: halo = left pad (exact)
        float v = 0.0f;                       // j<=1: exact; j>=2: warm-start

        f32x4 la0,la1,la2,la3,la4,la5,la6,la7;
        f32x4 lb0,lb1,lb2,lb3,lb4,lb5,lb6,lb7;
        RD8(la0,la1,la2,la3,la4,la5,la6,la7, sl, jl, 0)
        RD8(lb0,lb1,lb2,lb3,lb4,lb5,lb6,lb7, sl, jl, 8)
        if (j >= 1) { PHC(la0,la1,la2,la3,la4,la5,la6,la7, lb0.x) }

        f32x4 ca0,ca1,ca2,ca3,ca4,ca5,ca6,ca7;
        RD8(ca0,ca1,ca2,ca3,ca4,ca5,ca6,ca7, sl, j, 0)
        if (j >= 1) { PHC(lb0,lb1,lb2,lb3,lb4,lb5,lb6,lb7, ca0.x) }

        f32x4 cc0,cc1,cc2,cc3,cc4,cc5,cc6,cc7;
        RD8(cc0,cc1,cc2,cc3,cc4,cc5,cc6,cc7, sl, j, 8)
        const int jn = (j < 31) ? j + 1 : 0;
        const f32x4 pnv = *(const f32x4*)(sl + lgp(jn, 0));
        const float pn = (j < 31) ? pnv.x : 0.0f;   // right pad at row end

        f32x4 oa0,oa1,oa2,oa3,oa4,oa5,oa6,oa7;
        f32x4 ob0,ob1,ob2,ob3,ob4,ob5,ob6,ob7;
        Q4(ca0, ca1.x, oa0) Q4(ca1, ca2.x, oa1) Q4(ca2, ca3.x, oa2)
        Q4(ca3, ca4.x, oa3) Q4(ca4, ca5.x, oa4) Q4(ca5, ca6.x, oa5)
        Q4(ca6, ca7.x, oa6) Q4(ca7, cc0.x, oa7)
        Q4(cc0, cc1.x, ob0) Q4(cc1, cc2.x, ob1) Q4(cc2, cc3.x, ob2)
        Q4(cc3, cc4.x, ob3) Q4(cc4, cc5.x, ob4) Q4(cc5, cc6.x, ob5)
        Q4(cc6, cc7.x, ob6) Q4(cc7, pn,    ob7)

        // ---- output writeback (ALL input reads above in program order;
        // per-wave in-order DS pipe -> no cross-lane hazard)
        WR8(sl, j, 0, oa0,oa1,oa2,oa3,oa4,oa5,oa6,oa7)
        WR8(sl, j, 8, ob0,ob1,ob2,ob3,ob4,ob5,ob6,ob7)

        // ---- readback (coalescing transpose) for both rows
        f32x4 qA0,qA1,qA2,qA3,qA4,qA5,qA6,qA7;
        f32x4 qB0,qB1,qB2,qB3,qB4,qB5,qB6,qB7;
        RBROW(sA, qA0,qA1,qA2,qA3,qA4,qA5,qA6,qA7)
        RBROW(sB, qB0,qB1,qB2,qB3,qB4,qB5,qB6,qB7)

        // drain: prefetch (it=0) / stores (it=1) are >=1 full scan old
        __builtin_amdgcn_sched_barrier(0);
        asm volatile("s_waitcnt vmcnt(0)" ::: "memory");
        __builtin_amdgcn_sched_barrier(0);

        if (it == 0) {   // overwrite slices with next rows (readback done)
            DSWROW(sA, pA0,pA1,pA2,pA3,pA4,pA5,pA6,pA7)
            DSWROW(sB, pB0,pB1,pB2,pB3,pB4,pB5,pB6,pB7)
        }

        // ---- coalesced 1 KB stores, fire-and-forget
        float* oA = obase + (size_t)(it * 2) * T_;
        float* oB = oA + T_;
        STROW(oA, qA0,qA1,qA2,qA3,qA4,qA5,qA6,qA7)
        STROW(oB, qB0,qB1,qB2,qB3,qB4,qB5,qB6,qB7)
    }
}

extern "C" void kernel_launch(void* const* d_in, const int* in_sizes, int n_in,
                              void* d_out, int out_size, void* d_ws, size_t ws_size,
                              hipStream_t stream) {
    const float* x     = (const float*)d_in[0];
    const float* w     = (const float*)d_in[1];
    const float* cb    = (const float*)d_in[2];
    const float* gamma = (const float*)d_in[3];
    const float* beta  = (const float*)d_in[4];
    const float* rmean = (const float*)d_in[5];
    const float* rvar  = (const float*)d_in[6];
    float* out = (float*)d_out;

    // 8192 rows / (4 rows/wave x 2 waves/block) = 1024 blocks x 128 threads.
    const int grid = (B_ * C_) / 8;
    cpe_lif_kernel<<<grid, 128, 0, stream>>>(x, w, cb, gamma, beta, rmean, rvar, out);
}